// Round 10
// baseline (14966.068 us; speedup 1.0000x reference)
//
#include <hip/hip_runtime.h>
#include <stdint.h>

#define TSTEPS 512

typedef __attribute__((ext_vector_type(8))) _Float16 half8;
typedef __attribute__((ext_vector_type(4))) _Float16 half4;
typedef __attribute__((ext_vector_type(4))) float f32x4;
typedef __attribute__((ext_vector_type(4))) float float4v;
typedef __attribute__((ext_vector_type(4))) int i32x4;
typedef unsigned long long u64;

static __device__ __forceinline__ float sigm(float x) { return 1.f / (1.f + __expf(-x)); }
static __device__ __forceinline__ float tanh_(float x) {
  x = fminf(15.f, fmaxf(-15.f, x));
  float e = __expf(-2.f * x);
  return (1.f - e) / (1.f + e);
}
static __device__ __forceinline__ half8 ld8(const _Float16* p) { return *(const half8*)p; }
static __device__ __forceinline__ f32x4 MFMA(half8 a, half8 b, f32x4 c) {
  return __builtin_amdgcn_mfma_f32_16x16x32_f16(a, b, c, 0, 0, 0);
}

// ---- MALL primitives (agent scope, r4/r5-proven correct cross-XCD) ----
static __device__ __forceinline__ unsigned aadd(unsigned* p) {
  return __hip_atomic_fetch_add(p, 1u, __ATOMIC_RELAXED, __HIP_MEMORY_SCOPE_AGENT);
}
static __device__ __forceinline__ unsigned ald(const unsigned* p) {
  return __hip_atomic_load(p, __ATOMIC_RELAXED, __HIP_MEMORY_SCOPE_AGENT);
}
static __device__ __forceinline__ void ast(unsigned* p, unsigned v) {
  __hip_atomic_store(p, v, __ATOMIC_RELAXED, __HIP_MEMORY_SCOPE_AGENT);
}
static __device__ __forceinline__ u64 ald64(const u64* p) {
  return __hip_atomic_load(p, __ATOMIC_RELAXED, __HIP_MEMORY_SCOPE_AGENT);
}
static __device__ __forceinline__ void ast64(u64* p, u64 v) {
  __hip_atomic_store(p, v, __ATOMIC_RELAXED, __HIP_MEMORY_SCOPE_AGENT);
}

// ---- L2-point primitives: atomics WITHOUT sc1 execute at the XCD's L2.
// Atomics never hit/allocate L1 -> no stale-L1 hazard by construction.
static __device__ __forceinline__ void l2_st64(u64* p, u64 v) {
  asm volatile("global_atomic_swap_x2 %0, %1, off" :: "v"(p), "v"(v) : "memory");
}
static __device__ __forceinline__ void l2_st32(unsigned* p, unsigned v) {
  asm volatile("global_atomic_swap %0, %1, off" :: "v"(p), "v"(v) : "memory");
}
static __device__ __forceinline__ unsigned l2_ld32(const unsigned* p) {
  unsigned r, z = 0;
  asm volatile("global_atomic_add %0, %1, %2, off sc0\n\ts_waitcnt vmcnt(0)"
               : "=&v"(r) : "v"(p), "v"(z) : "memory");
  return r;
}
// 8 x u64 atomic reads (add-0, return-old) batched under one vmcnt drain
static __device__ __forceinline__ void l2_ld_frag(
    const u64* p0, const u64* p1, const u64* p2, const u64* p3, u64* m) {
  u64 z = 0;
  asm volatile(
    "global_atomic_add_x2 %0, %8, %12, off sc0\n\t"
    "global_atomic_add_x2 %1, %8, %12, off offset:8 sc0\n\t"
    "global_atomic_add_x2 %2, %9, %12, off sc0\n\t"
    "global_atomic_add_x2 %3, %9, %12, off offset:8 sc0\n\t"
    "global_atomic_add_x2 %4, %10, %12, off sc0\n\t"
    "global_atomic_add_x2 %5, %10, %12, off offset:8 sc0\n\t"
    "global_atomic_add_x2 %6, %11, %12, off sc0\n\t"
    "global_atomic_add_x2 %7, %11, %12, off offset:8 sc0\n\t"
    "s_waitcnt vmcnt(0)"
    : "=&v"(m[0]), "=&v"(m[1]), "=&v"(m[2]), "=&v"(m[3]),
      "=&v"(m[4]), "=&v"(m[5]), "=&v"(m[6]), "=&v"(m[7])
    : "v"(p0), "v"(p1), "v"(p2), "v"(p3), "v"(z)
    : "memory");
}

// ---------------- f32 -> f16 conversion ----------------
__global__ __launch_bounds__(256) void kconv(
    const float* __restrict__ xs, const float* __restrict__ wih,
    const float* __restrict__ wxh, const float* __restrict__ whhf,
    const float* __restrict__ wrf,
    _Float16* __restrict__ xs_h, _Float16* __restrict__ wcat,
    _Float16* __restrict__ whh, _Float16* __restrict__ wr) {
  const long n1 = 8388608, n2 = 1048576, n3 = 786432, n4 = 262144;
  const long total = n1 + n2 + n3 + n4;
  for (long i = (long)blockIdx.x * 256 + threadIdx.x; i < total; i += (long)gridDim.x * 256) {
    const float* s; _Float16* d;
    if (i < n1) { s = xs + i * 4; d = xs_h + i * 4; }
    else if (i < n1 + n2) {
      long e = (i - n1) * 4;
      s = (e < 3145728) ? (wih + e) : (wxh + (e - 3145728));
      d = wcat + e;
    } else if (i < n1 + n2 + n3) { long e = (i - n1 - n2) * 4; s = whhf + e; d = whh + e; }
    else { long e = (i - n1 - n2 - n3) * 4; s = wrf + e; d = wr + e; }
    float4v v = *(const float4v*)s;
    half4 o = { (_Float16)v.x, (_Float16)v.y, (_Float16)v.z, (_Float16)v.w };
    *(half4*)d = o;
  }
}

// ---------------- big input-side GEMM ----------------
__global__ __launch_bounds__(256) void kgemm(
    const _Float16* __restrict__ X, const _Float16* __restrict__ W,
    const float* __restrict__ b_ih, const float* __restrict__ b_xh,
    _Float16* __restrict__ C) {
  __shared__ _Float16 As[128 * 40], Bs[128 * 40];
  const int tid = threadIdx.x;
  const int lane = tid & 63;
  const int w = tid >> 6;
  const int wm = (w >> 1) * 64, wn = (w & 1) * 64;
  const int bn = blockIdx.x * 128;
  const int bm = blockIdx.y * 128;
  const int arow = tid >> 2;
  const int kk8 = (tid & 3) * 8;
  const int fr = lane & 15, fq = lane >> 4;
  const f32x4 zero = {0.f, 0.f, 0.f, 0.f};
  f32x4 acc[4][4];
  #pragma unroll
  for (int a = 0; a < 4; a++)
    #pragma unroll
    for (int b = 0; b < 4; b++) acc[a][b] = zero;
  for (int kt = 0; kt < 1024; kt += 32) {
    __syncthreads();
    #pragma unroll
    for (int j = 0; j < 2; j++) {
      int r = j * 64 + arow;
      *(half8*)(As + r * 40 + kk8) = ld8(X + (size_t)(bm + r) * 1024 + kt + kk8);
      *(half8*)(Bs + r * 40 + kk8) = ld8(W + (size_t)(bn + r) * 1024 + kt + kk8);
    }
    __syncthreads();
    half8 af[4], bfr[4];
    #pragma unroll
    for (int i = 0; i < 4; i++) {
      af[i]  = *(const half8*)(As + (wm + i * 16 + fr) * 40 + fq * 8);
      bfr[i] = *(const half8*)(Bs + (wn + i * 16 + fr) * 40 + fq * 8);
    }
    #pragma unroll
    for (int mi = 0; mi < 4; mi++)
      #pragma unroll
      for (int ni = 0; ni < 4; ni++)
        acc[mi][ni] = MFMA(af[mi], bfr[ni], acc[mi][ni]);
  }
  #pragma unroll
  for (int mi = 0; mi < 4; mi++)
    #pragma unroll
    for (int ni = 0; ni < 4; ni++) {
      int col = bn + wn + ni * 16 + fr;
      float bias = (col < 3072) ? b_ih[col] : b_xh[col - 3072];
      #pragma unroll
      for (int r = 0; r < 4; r++) {
        int row = bm + wm + mi * 16 + fq * 4 + r;
        C[(size_t)row * 4096 + col] = (_Float16)(acc[mi][ni][r] + bias);
      }
    }
}

// ---------------- persistent recurrent kernel ----------------
// 4 groups x 16 rows x 32 wgs x 512 thr (r4-proven geometry).
// LOCAL: group == XCD; exchange via L2-point atomics (fast flags base-epoch'd,
// MALL truth flags backstop liveness). Fallback: r5 MALL protocol.
#define RP 20
#define TP (16 * RP)

template<int LOCAL>
static __device__ __forceinline__ void waitf(
    const unsigned* fl, unsigned ftag, const unsigned* tr, unsigned ttag) {
  if (LOCAL) {
    if ((threadIdx.x >> 6) == 0) {
      const unsigned* p = fl + (threadIdx.x & 31);
      const unsigned* q = tr + (threadIdx.x & 31);
      int it = 0;
      for (;;) {
        if (__all(l2_ld32(p) >= ftag)) break;
        ++it;
        if ((it & 63) == 0) {
          if (__all(ald(q) >= ttag)) break;   // liveness backstop (MALL truth)
          if (it > 200000) break;             // hard bound: never hang 600s
        }
        __builtin_amdgcn_s_sleep(1);
      }
    }
    __syncthreads();
  } else {
    const unsigned* q = tr + (threadIdx.x & 31);
    while (!__all(ald(q) >= ttag))
      __builtin_amdgcn_s_sleep(1);
  }
  asm volatile("" ::: "memory");
}

template<int LOCAL>
static __device__ void run_rec(
    int tid, int grp, int slot, unsigned base,
    const _Float16* __restrict__ xgh, const float* __restrict__ ms,
    const _Float16* __restrict__ whh, const _Float16* __restrict__ wr,
    const float* __restrict__ b_hh, const float* __restrict__ b_r,
    const float* __restrict__ h0,
    u64* __restrict__ hx, u64* __restrict__ rhx,
    unsigned* __restrict__ truth, unsigned* __restrict__ flagsL,
    float* __restrict__ out, float* red) {
  const int lane = tid & 63, w = tid >> 6;
  const int fr = lane & 15, fq = lane >> 4;
  const int colbase = slot * 32;
  unsigned* flA = flagsL + grp * 64;        // L2 fast flags (base-epoch)
  unsigned* flB = flagsL + grp * 64 + 32;
  unsigned* trA = truth + grp * 64;         // MALL truth flags (memset 0)
  unsigned* trB = truth + grp * 64 + 32;

  // ---- weight fragments -> registers (resident; unified VGPR/AGPR file)
  half8 wA[6][4], wB[2][4];
  #pragma unroll
  for (int nt = 0; nt < 6; nt++)
    #pragma unroll
    for (int ks = 0; ks < 4; ks++)
      wA[nt][ks] = ld8(whh + (size_t)((nt >> 1) * 1024 + colbase + (nt & 1) * 16 + fr) * 1024
                            + w * 128 + ks * 32 + fq * 8);
  #pragma unroll
  for (int nt = 0; nt < 2; nt++)
    #pragma unroll
    for (int ks = 0; ks < 4; ks++)
      wB[nt][ks] = ld8(wr + (size_t)(colbase + nt * 16 + fr) * 1024
                           + w * 128 + ks * 32 + fq * 8);

  // ---- every thread owns one (row b, col cc) cell
  const int b = tid >> 5, cc = tid & 31;
  const int gc = colbase + cc;
  const int gm = grp * 16 + b;
  const float bhr = b_hh[gc], bhz = b_hh[1024 + gc], bhe = b_hh[2048 + gc];
  const float brr = b_r[gc];
  float hreg = h0[(size_t)gm * 1024 + gc];

  // msg addressing (u64 units): row stride 256, parity stride 16384
  const u64* hcons = hx  + (size_t)(grp * 16 + fr) * 256 + w * 32 + fq * 2;
  const u64* rcons = rhx + (size_t)(grp * 16 + fr) * 256 + w * 32 + fq * 2;
  u64* hprod = hx  + (size_t)gm * 256 + (gc >> 2);
  u64* rprod = rhx + (size_t)gm * 256 + (gc >> 2);

  const f32x4 zero = {0.f, 0.f, 0.f, 0.f};

  float pxr, pxz, pxe, pxh, ptm;
  {
    const _Float16* xp = xgh + (size_t)gm * 4096;
    pxr = (float)xp[gc]; pxz = (float)xp[1024 + gc];
    pxe = (float)xp[2048 + gc]; pxh = (float)xp[3072 + gc];
    ptm = tanh_(ms[(size_t)gm * 1024 + gc]);
  }

  #pragma clang loop unroll(disable)
  for (int t = 0; t < TSTEPS; t++) {
    const int ph = t & 1;
    // ======== phase A: h(t) -> gates; publish rh(t)
    half8 av[4];
    if (t == 0) {
      const float* hp = h0 + (size_t)(grp * 16 + fr) * 1024 + w * 128 + fq * 8;
      #pragma unroll
      for (int ks = 0; ks < 4; ks++) {
        float4v a = *(const float4v*)(hp + ks * 32);
        float4v c = *(const float4v*)(hp + ks * 32 + 4);
        half8 h = { (_Float16)a.x, (_Float16)a.y, (_Float16)a.z, (_Float16)a.w,
                    (_Float16)c.x, (_Float16)c.y, (_Float16)c.z, (_Float16)c.w };
        av[ks] = h;
      }
    } else {
      waitf<LOCAL>(flB, base + (unsigned)t, trB, (unsigned)t);
      const u64* c0 = hcons + ph * 16384;
      if (LOCAL) {
        u64 m[8];
        l2_ld_frag(c0, c0 + 8, c0 + 16, c0 + 24, m);
        #pragma unroll
        for (int ks = 0; ks < 4; ks++) {
          struct { u64 a, b; } u{m[2 * ks], m[2 * ks + 1]};
          av[ks] = __builtin_bit_cast(half8, u);
        }
      } else {
        #pragma unroll
        for (int ks = 0; ks < 4; ks++) {
          struct { u64 a, b; } u{ald64(c0 + ks * 8), ald64(c0 + ks * 8 + 1)};
          av[ks] = __builtin_bit_cast(half8, u);
        }
      }
    }
    f32x4 accA[6];
    #pragma unroll
    for (int nt = 0; nt < 6; nt++) accA[nt] = zero;
    #pragma unroll
    for (int ks = 0; ks < 4; ks++)
      #pragma unroll
      for (int nt = 0; nt < 6; nt++)
        accA[nt] = MFMA(av[ks], wA[nt][ks], accA[nt]);
    #pragma unroll
    for (int nt = 0; nt < 6; nt++)
      #pragma unroll
      for (int r = 0; r < 4; r++)
        red[(w * 6 + nt) * TP + (fq * 4 + r) * RP + fr] = accA[nt][r];
    __syncthreads();                              // S1
    float sr = pxr + bhr, sz = pxz + bhz, se = pxe + bhe;
    {
      const int boff = b * RP + (cc & 15) + (cc >> 4) * TP;
      #pragma unroll
      for (int w8 = 0; w8 < 8; w8++) {
        const float* rp = red + w8 * 6 * TP + boff;
        sr += rp[0]; sz += rp[2 * TP]; se += rp[4 * TP];
      }
    }
    float rg = sigm(sr);
    float zz = sigm(sz), ee = sigm(se);
    {
      float rv = rg * hreg;
      unsigned us = (unsigned)(unsigned short)__builtin_bit_cast(unsigned short, (_Float16)rv);
      unsigned v01 = us | (((unsigned)__shfl_down((int)us, 1) & 0xFFFFu) << 16);
      unsigned v23 = (unsigned)__shfl_down((int)v01, 2);
      if (!(cc & 3)) {
        u64 pv = ((u64)v23 << 32) | (u64)v01;
        if (LOCAL) l2_st64(rprod + ph * 16384, pv);
        else       ast64(rprod + ph * 16384, pv);
      }
    }
    asm volatile("s_waitcnt vmcnt(0)" ::: "memory");
    __syncthreads();                              // S2: rh acked at L2/MALL
    if (tid == 0) {
      if (LOCAL) l2_st32(flA + slot, base + (unsigned)(t + 1));
      ast(trA + slot, (unsigned)(t + 1));
    }
    float nxr = 0, nxz = 0, nxe = 0, nxh = 0, ntm = 0;
    if (t + 1 < TSTEPS) {
      const _Float16* xp = xgh + (size_t)((t + 1) * 64 + gm) * 4096;
      nxr = (float)xp[gc]; nxz = (float)xp[1024 + gc];
      nxe = (float)xp[2048 + gc]; nxh = (float)xp[3072 + gc];
      ntm = tanh_(ms[(size_t)(t + 1) * 65536 + gm * 1024 + gc]);
    }

    // ======== phase B: rh(t) -> hhat; h update; publish h(t+1)
    waitf<LOCAL>(flA, base + (unsigned)(t + 1), trA, (unsigned)(t + 1));
    half8 bv[4];
    {
      const u64* c0 = rcons + ph * 16384;
      if (LOCAL) {
        u64 m[8];
        l2_ld_frag(c0, c0 + 8, c0 + 16, c0 + 24, m);
        #pragma unroll
        for (int ks = 0; ks < 4; ks++) {
          struct { u64 a, b; } u{m[2 * ks], m[2 * ks + 1]};
          bv[ks] = __builtin_bit_cast(half8, u);
        }
      } else {
        #pragma unroll
        for (int ks = 0; ks < 4; ks++) {
          struct { u64 a, b; } u{ald64(c0 + ks * 8), ald64(c0 + ks * 8 + 1)};
          bv[ks] = __builtin_bit_cast(half8, u);
        }
      }
    }
    f32x4 accB[2];
    #pragma unroll
    for (int nt = 0; nt < 2; nt++) accB[nt] = zero;
    #pragma unroll
    for (int ks = 0; ks < 4; ks++)
      #pragma unroll
      for (int nt = 0; nt < 2; nt++)
        accB[nt] = MFMA(bv[ks], wB[nt][ks], accB[nt]);
    #pragma unroll
    for (int nt = 0; nt < 2; nt++)
      #pragma unroll
      for (int r = 0; r < 4; r++)
        red[(w * 6 + nt) * TP + (fq * 4 + r) * RP + fr] = accB[nt][r];
    __syncthreads();                              // S3
    float s = pxh + brr;
    {
      const int boff = b * RP + (cc & 15) + (cc >> 4) * TP;
      #pragma unroll
      for (int w8 = 0; w8 < 8; w8++) s += red[w8 * 6 * TP + boff];
    }
    float hh = tanh_(s);
    float hn = zz * hreg + (1.f - zz) * hh + ee * ptm;
    hreg = hn;
    {
      unsigned us = (unsigned)(unsigned short)__builtin_bit_cast(unsigned short, (_Float16)hn);
      unsigned v01 = us | (((unsigned)__shfl_down((int)us, 1) & 0xFFFFu) << 16);
      unsigned v23 = (unsigned)__shfl_down((int)v01, 2);
      if (!(cc & 3)) {
        u64 pv = ((u64)v23 << 32) | (u64)v01;
        if (LOCAL) l2_st64(hprod + (ph ^ 1) * 16384, pv);
        else       ast64(hprod + (ph ^ 1) * 16384, pv);
      }
    }
    asm volatile("s_waitcnt vmcnt(0)" ::: "memory");
    __syncthreads();                              // S4: h acked
    if (tid == 0) {
      if (LOCAL) l2_st32(flB + slot, base + (unsigned)(t + 1));
      ast(trB + slot, (unsigned)(t + 1));
    }
    __builtin_nontemporal_store(hn, out + (size_t)t * 65536 + gm * 1024 + gc);
    pxr = nxr; pxz = nxz; pxe = nxe; pxh = nxh; ptm = ntm;
  }
  out[(size_t)TSTEPS * 65536 + gm * 1024 + gc] = hreg;
}

__global__ __launch_bounds__(512, 2) void krec(
    const _Float16* __restrict__ xgh, const float* __restrict__ ms,
    const _Float16* __restrict__ whh, const _Float16* __restrict__ wr,
    const float* __restrict__ b_hh, const float* __restrict__ b_r,
    const float* __restrict__ h0,
    u64* __restrict__ hx, u64* __restrict__ rhx,
    float* __restrict__ out, unsigned* __restrict__ ctr,
    unsigned* __restrict__ flagsL) {
  __shared__ float red[48 * TP];
  __shared__ int sh[2];
  __shared__ unsigned bsh;
  const int tid = threadIdx.x;
  unsigned* reg = ctr;            // [0..7] XCD census, [8] bar1, [9] bar2
  unsigned* truth = ctr + 64;     // 4 grp x 64 truth flags (memset 0)

  // ---- census: XCD placement + consistent global mode decision
  if (tid == 0) {
    unsigned x;
    asm volatile("s_getreg_b32 %0, hwreg(HW_REG_XCC_ID)" : "=s"(x));
    x &= 7u;
    unsigned slot = aadd(&reg[x]);
    asm volatile("s_waitcnt vmcnt(0)" ::: "memory");
    aadd(&reg[8]);
    unsigned cnt = 0;
    for (long it = 0; it < 4000000; ++it) {
      cnt = ald(&reg[8]);
      if (cnt >= 256u) break;
      __builtin_amdgcn_s_sleep(8);
    }
    int ok = (cnt >= 256u);
    if (ok)
      #pragma unroll
      for (int i = 0; i < 8; i++) ok &= (ald(&reg[i]) == 32u);
    sh[0] = ok; sh[1] = (int)(x * 32u + (slot & 31u));
  }
  __syncthreads();

  if (sh[0]) {
    const int grp = sh[1] >> 5, slot = sh[1] & 31;
    if (grp >= 4) return;                      // XCDs 4-7 idle in LOCAL mode
    // base-epoch: agree on max of the group's L2 flag words (pre-activity)
    unsigned v = 0;
    if (tid < 64) v = l2_ld32(flagsL + grp * 64 + tid);
    if (tid == 0) bsh = 0;
    __syncthreads();
    if (tid < 64) atomicMax(&bsh, v);
    __syncthreads();
    const unsigned base = bsh;
    if (tid == 0) {                            // census barrier 2 (128 wgs)
      aadd(&reg[9]);
      for (long it = 0; it < 4000000; ++it) {
        if (ald(&reg[9]) >= 128u) break;
        __builtin_amdgcn_s_sleep(8);
      }
    }
    __syncthreads();
    run_rec<1>(tid, grp, slot, base, xgh, ms, whh, wr, b_hh, b_r, h0,
               hx, rhx, truth, flagsL, out, red);
  } else {
    const int bid = (int)blockIdx.x;
    if (bid >= 128) return;
    run_rec<0>(tid, bid >> 5, bid & 31, 0u, xgh, ms, whh, wr, b_hh, b_r, h0,
               hx, rhx, truth, flagsL, out, red);
  }
}

extern "C" void kernel_launch(void* const* d_in, const int* in_sizes, int n_in,
                              void* d_out, int out_size, void* d_ws, size_t ws_size,
                              hipStream_t stream) {
  const float* xs   = (const float*)d_in[0];
  const float* ms   = (const float*)d_in[1];
  const float* h0   = (const float*)d_in[2];
  const float* W_ih = (const float*)d_in[3];
  const float* b_ih = (const float*)d_in[4];
  const float* W_hh = (const float*)d_in[5];
  const float* b_hh = (const float*)d_in[6];
  const float* W_xh = (const float*)d_in[7];
  const float* b_xh = (const float*)d_in[8];
  const float* W_r  = (const float*)d_in[9];
  const float* b_r  = (const float*)d_in[10];

  char* ws = (char*)d_ws;
  size_t off = 0;
  _Float16* xs_h = (_Float16*)(ws + off); off += 67108864;   // [32768][1024] f16
  _Float16* wcat = (_Float16*)(ws + off); off += 8388608;    // [4096][1024] f16
  _Float16* whh  = (_Float16*)(ws + off); off += 6291456;    // [3072][1024] f16
  _Float16* wr   = (_Float16*)(ws + off); off += 2097152;    // [1024][1024] f16
  _Float16* xgh  = (_Float16*)(ws + off); off += 268435456;  // [32768][4096] f16
  u64* hx   = (u64*)(ws + off); off += 262144;  // [2 par][64 rows][256 u64]
  u64* rhx  = (u64*)(ws + off); off += 262144;
  unsigned* ctr = (unsigned*)(ws + off); off += 4096;   // census + truth (memset)
  unsigned* flagsL = (unsigned*)(ws + off); off += 4096; // L2 flags (NOT memset; base-epoch)

  hipMemsetAsync(ctr, 0, 4096, stream);
  kconv<<<2048, 256, 0, stream>>>(xs, W_ih, W_xh, W_hh, W_r,
                                  xs_h, wcat, whh, wr);
  kgemm<<<dim3(32, 256), 256, 0, stream>>>(xs_h, wcat, b_ih, b_xh, xgh);
  krec<<<256, 512, 0, stream>>>(xgh, ms, whh, wr, b_hh, b_r, h0,
                                hx, rhx, (float*)d_out, ctr, flagsL);
}